// Round 5
// baseline (375.272 us; speedup 1.0000x reference)
//
#include <hip/hip_runtime.h>

// GumbelSlotSelector via MFMA: layer1 (524288x64x128 fp32 GEMM) as 6-term
// exact 3xbf16-split MFMA; layer2 + gumbel + ballot fixup fused per-wave.
//
// THIS REVISION: contiguous DMA. The previous k-sliced staging issued
// global_load_lds with 16B/lane at 32B stride over 512B-strided rows (64
// scattered requests/instr) -> request-path limited at 2.5 TB/s. Now staging
// is mt-major: each wave stages 16 full rows (8 KB) per chunk as 8x 1KB
// CONTIGUOUS dma16 instructions. The lane->granule assignment within each
// 1KB is XOR-permuted (i ^ (row&7)) so the MFMA-fragment ds_read_b128
// pattern is bank-conflict-free (DMA dest must stay linear; the permutation
// rides on the per-lane GLOBAL address -- the 1KB set stays contiguous).
// Per chunk: wait vmcnt(0) [precise: next chunk not yet issued], ds_read all
// fragments to regs, lgkmcnt(0), issue next chunk's DMAs, then convert+MFMA
// with 8 KB in flight; next-tile chunk flies under the epilogue.
// Staged bytes, convert order, and per-chain MFMA order are bit-identical.

typedef __attribute__((ext_vector_type(8))) short bf16x8;
typedef __attribute__((ext_vector_type(4))) float f32x4;

constexpr int NROWS = 8192 * 64;   // 524288
constexpr int D = 128;

typedef const __attribute__((address_space(1))) unsigned int gbl_u32;
typedef __attribute__((address_space(3))) unsigned int lds_u32;

__device__ __forceinline__ void dma16(const float* g, float* l) {
    // async global->LDS, 16 B/lane; LDS dest = uniform base + lane*16
    __builtin_amdgcn_global_load_lds((gbl_u32*)g, (lds_u32*)l, 16, 0, 0);
}

__device__ __forceinline__ void split3(float x, unsigned& h1, unsigned& h2, unsigned& h3) {
    unsigned ux = __float_as_uint(x);
    h1 = ux & 0xFFFF0000u;                       // top 8 mantissa bits
    float r = x - __uint_as_float(h1);           // exact
    h2 = __float_as_uint(r) & 0xFFFF0000u;       // next 8
    float r2 = r - __uint_as_float(h2);          // exact
    h3 = __float_as_uint(r2) & 0xFFFF0000u;      // remaining bits (exact)
}

__global__ __launch_bounds__(512, 2)
void gumbel_slot_mfma(const float* __restrict__ slots,
                      const float* __restrict__ gumbel_u,
                      const float* __restrict__ fix_u,
                      const float* __restrict__ W1,
                      const float* __restrict__ b1,
                      const float* __restrict__ W2,
                      const float* __restrict__ b2,
                      float* __restrict__ out)
{
    __shared__ __align__(16) unsigned short wt[3 * 64 * 128];  // 48 KB W1 splits
    __shared__ __align__(16) float red[8][16][16][2];          // 16 KB epilogue
    __shared__ __align__(16) float stg[8][2048];               // 64 KB: 8 KB/wave

    const int tid  = threadIdx.x;
    const int wv   = tid >> 6;        // wave 0..7
    const int lane = tid & 63;
    const int quad = lane >> 4;       // 0..3
    const int col  = lane & 15;       // 0..15
    const int colx = col & 7;         // read-side XOR mask

    float* stgW = &stg[wv][0];

    const int tile0 = blockIdx.x * 4;               // 4 consecutive tiles/block
    const int row0  = tile0 * 512 + wv * 64;        // wave's first row

    // DMA lane geometry: instr j covers buffer rows {2j, 2j+1} (full 512 B);
    // lane lands at LDS slot (r = 2j + lane>>5, i_slot = lane&31); it must
    // FETCH granule i = i_slot ^ (r&7)  (same contiguous 1 KB set).
    const int lrow = lane >> 5;       // 0..1: which of the 2 rows
    const int lgrn = lane & 31;       // granule slot within row

    // ---- prologue: stage chunk (t=0, mt=0) contiguously ----
#pragma unroll
    for (int j = 0; j < 8; ++j) {
        const int rsub = 2 * j + lrow;
        dma16(slots + (size_t)(row0 + rsub) * D + ((lgrn ^ (rsub & 7)) << 2),
              stgW + j * 256);
    }

    // ---- one-time: split W1 into 3 bf16 planes, transposed [j][d] ----
#pragma unroll
    for (int i = 0; i < 16; ++i) {
        const int e = i * 512 + tid;          // 8192 elements, coalesced
        const int d = e >> 6, j = e & 63;
        unsigned h1, h2, h3;
        split3(W1[e], h1, h2, h3);
        const int chunk = (d >> 3) ^ (j & 15);           // 16B-chunk swizzle
        const int idx = j * 128 + chunk * 8 + (d & 7);
        wt[idx]             = (unsigned short)(h1 >> 16);
        wt[idx + 8192]      = (unsigned short)(h2 >> 16);
        wt[idx + 16384]     = (unsigned short)(h3 >> 16);
    }

    // per-lane constants + ALL gumbel pairs (pre-barrier)
    float  b1v[4];
    float2 w2v[4];
#pragma unroll
    for (int nt = 0; nt < 4; ++nt) {
        b1v[nt] = b1[nt * 16 + col];
        w2v[nt] = *(const float2*)(W2 + (size_t)(nt * 16 + col) * 2);
    }
    const float2 b2v = *(const float2*)b2;
    float2 gu0, gu1, gu2, gu3;
    {
        const size_t rb = (size_t)(row0 + lane);
        gu0 = *(const float2*)(gumbel_u + (rb         ) * 2);
        gu1 = *(const float2*)(gumbel_u + (rb +  512  ) * 2);
        gu2 = *(const float2*)(gumbel_u + (rb + 1024  ) * 2);
        gu3 = *(const float2*)(gumbel_u + (rb + 1536  ) * 2);
    }

    __syncthreads();   // wt ready; drains prologue DMA + preamble loads

#pragma unroll 1
    for (int t = 0; t < 4; ++t) {
        const int rowW = (tile0 + t) * 512 + wv * 64;    // this wave's 64 rows
        const int r    = rowW + lane;

        f32x4 acc[4][4];
#pragma unroll
        for (int mt = 0; mt < 4; ++mt)
#pragma unroll
            for (int nt = 0; nt < 4; ++nt)
                acc[mt][nt] = f32x4{b1v[nt], b1v[nt], b1v[nt], b1v[nt]};

#pragma unroll
        for (int mt = 0; mt < 4; ++mt) {
            // ---- current chunk is the ONLY outstanding traffic: precise drain ----
            asm volatile("s_waitcnt vmcnt(0)" ::: "memory");
            __builtin_amdgcn_sched_barrier(0);

            // ---- read this mt's fragments: row=col, granules i0,i0+1 per ks ----
            f32x4 va[4], vb[4];
#pragma unroll
            for (int ks = 0; ks < 4; ++ks) {
                const int i0 = ks * 8 + quad * 2;
                va[ks] = *(const f32x4*)(stgW + col * 128 + (((i0    ) ^ colx) << 2));
                vb[ks] = *(const f32x4*)(stgW + col * 128 + (((i0 + 1) ^ colx) << 2));
            }
            asm volatile("s_waitcnt lgkmcnt(0)" ::: "memory");
            __builtin_amdgcn_sched_barrier(0);

            // ---- issue NEXT chunk's 8 contiguous DMAs (flies under compute) ----
            if (!(t == 3 && mt == 3)) {
                const int rowNbase = (mt < 3) ? (rowW + (mt + 1) * 16)
                                              : (rowW + 512);     // next tile, mt0
#pragma unroll
                for (int j = 0; j < 8; ++j) {
                    const int rsub = 2 * j + lrow;
                    dma16(slots + (size_t)(rowNbase + rsub) * D
                                + ((lgrn ^ (rsub & 7)) << 2),
                          stgW + j * 256);
                }
            }

            // ---- convert + MFMA (order bit-identical per accumulator chain) ----
#pragma unroll
            for (int ks = 0; ks < 4; ++ks) {
                const float xs[8] = {va[ks][0], va[ks][1], va[ks][2], va[ks][3],
                                     vb[ks][0], vb[ks][1], vb[ks][2], vb[ks][3]};
                union { int i[4]; bf16x8 vv; } u1, u2, u3;
#pragma unroll
                for (int p = 0; p < 4; ++p) {
                    unsigned xh1, xh2, xh3, yh1, yh2, yh3;
                    split3(xs[2 * p],     xh1, xh2, xh3);
                    split3(xs[2 * p + 1], yh1, yh2, yh3);
                    u1.i[p] = (int)((xh1 >> 16) | yh1);  // [k even | k odd]
                    u2.i[p] = (int)((xh2 >> 16) | yh2);
                    u3.i[p] = (int)((xh3 >> 16) | yh3);
                }
                const bf16x8 a1 = u1.vv, a2 = u2.vv, a3 = u3.vv;

                __builtin_amdgcn_s_setprio(1);
#pragma unroll
                for (int nt = 0; nt < 4; ++nt) {
                    const int j = nt * 16 + col;
                    const int chunk = (ks * 4 + quad) ^ col;
                    const unsigned short* wp = &wt[j * 128 + chunk * 8];
                    const bf16x8 bq1 = *(const bf16x8*)(wp);
                    const bf16x8 bq2 = *(const bf16x8*)(wp + 8192);
                    const bf16x8 bq3 = *(const bf16x8*)(wp + 16384);
                    f32x4 c = acc[mt][nt];
                    c = __builtin_amdgcn_mfma_f32_16x16x32_bf16(a1, bq1, c, 0, 0, 0);
                    c = __builtin_amdgcn_mfma_f32_16x16x32_bf16(a2, bq1, c, 0, 0, 0);
                    c = __builtin_amdgcn_mfma_f32_16x16x32_bf16(a1, bq2, c, 0, 0, 0);
                    c = __builtin_amdgcn_mfma_f32_16x16x32_bf16(a2, bq2, c, 0, 0, 0);
                    c = __builtin_amdgcn_mfma_f32_16x16x32_bf16(a1, bq3, c, 0, 0, 0);
                    c = __builtin_amdgcn_mfma_f32_16x16x32_bf16(a3, bq1, c, 0, 0, 0);
                    acc[mt][nt] = c;
                }
                __builtin_amdgcn_s_setprio(0);
            }
        }

        // ---- epilogue: layer2 partials + per-row transpose via LDS ----
        // Fully unrolled (static acc indices); red[wv] is wave-private.
        float fl0 = 0.f, fl1 = 0.f;
#pragma unroll
        for (int mt = 0; mt < 4; ++mt) {
#pragma unroll
            for (int reg = 0; reg < 4; ++reg) {
                float p0 = 0.f, p1 = 0.f;
#pragma unroll
                for (int nt = 0; nt < 4; ++nt) {
                    const float h = fmaxf(acc[mt][nt][reg], 0.f);
                    p0 = fmaf(h, w2v[nt].x, p0);
                    p1 = fmaf(h, w2v[nt].y, p1);
                }
                const int rl = quad * 4 + reg;
                *(float2*)&red[wv][rl][col ^ rl][0] = make_float2(p0, p1);
            }
            __builtin_amdgcn_wave_barrier();
            if (quad == mt) {
                const int rl = col;
                float s0 = 0.f, s1 = 0.f;
#pragma unroll
                for (int c = 0; c < 16; ++c) {
                    const float2 vv = *(const float2*)&red[wv][rl][c ^ rl][0];
                    s0 += vv.x; s1 += vv.y;
                }
                fl0 = s0; fl1 = s1;
            }
            __builtin_amdgcn_wave_barrier();
        }
        const float l0 = fl0 + b2v.x;
        const float l1 = fl1 + b2v.y;

        // ---- gumbel decision + keep prob ----
        const float2 guv = (t == 0) ? gu0 : ((t == 1) ? gu1 : ((t == 2) ? gu2 : gu3));
        const float lo = 1e-10f, hi = (float)(1.0 - 1e-7);
        const float u0 = fminf(fmaxf(guv.x, lo), hi);
        const float u1 = fminf(fmaxf(guv.y, lo), hi);
        const float g0 = -logf(-logf(u0));
        const float g1 = -logf(-logf(u1));
        float dec = ((l1 + g1) > (l0 + g0)) ? 1.0f : 0.0f;

        const float m  = fmaxf(l0, l1);
        const float e0 = expf(l0 - m), e1 = expf(l1 - m);
        const float keep = e1 / (e0 + e1);

        // ensure-minimum: this wave's 64 lanes == one b's 64 slots
        const unsigned long long act = __ballot(dec != 0.0f);
        if (act == 0ull) {
            float v = fix_u[r];
            int  idx = lane;
#pragma unroll
            for (int off = 32; off > 0; off >>= 1) {
                const float ov  = __shfl_xor(v, off, 64);
                const int  oidx = __shfl_xor(idx, off, 64);
                if (ov > v || (ov == v && oidx < idx)) { v = ov; idx = oidx; }
            }
            if (lane == idx) dec = 1.0f;
        }

        out[r] = dec;
        out[NROWS + r] = keep;
    }
}

extern "C" void kernel_launch(void* const* d_in, const int* in_sizes, int n_in,
                              void* d_out, int out_size, void* d_ws, size_t ws_size,
                              hipStream_t stream)
{
    const float* slots  = (const float*)d_in[0];
    const float* gumbel = (const float*)d_in[1];
    const float* fixu   = (const float*)d_in[2];
    const float* W1     = (const float*)d_in[3];
    const float* b1     = (const float*)d_in[4];
    const float* W2     = (const float*)d_in[5];
    const float* b2     = (const float*)d_in[6];
    float* out = (float*)d_out;

    gumbel_slot_mfma<<<256, 512, 0, stream>>>(
        slots, gumbel, fixu, W1, b1, W2, b2, out);
}

// Round 6
// 373.252 us; speedup vs baseline: 1.0054x; 1.0054x over previous
//
#include <hip/hip_runtime.h>

// GumbelSlotSelector via MFMA: layer1 (524288x64x128 fp32 GEMM) as 6-term
// exact 3xbf16-split MFMA; layer2 + gumbel + ballot fixup fused per-wave.
//
// THIS REVISION: two-path hybrid staging. Evidence: r4 (counted vmcnt, 4KB
// chunks) and r5 (precise drain, 8KB chunks) tie at ~111us kernel / 2.5 TB/s
// -- per-wave in-flight (~8KB) is the invariant, LDS-walled. r3's spilling
// kernel proved DMA + independent vector-load streams SUM (4.55 TB/s). So:
// rows 0..7 of each mt-subtile go global_load_lds -> double-buffered 4KB LDS;
// rows 8..15 go direct global_load_dwordx4 -> double-buffered VGPR sets
// (col>=8 lanes, one phase ahead, compile-time parity mt&1). Both paths
// issue at phase start; s_waitcnt vmcnt(12) keeps the next phase's 12 ops in
// flight. Staged bytes, granules, convert order, and per-chain MFMA order
// are bit-identical to the passing kernel.

typedef __attribute__((ext_vector_type(8))) short bf16x8;
typedef __attribute__((ext_vector_type(4))) float f32x4;

constexpr int NROWS = 8192 * 64;   // 524288
constexpr int D = 128;

typedef const __attribute__((address_space(1))) unsigned int gbl_u32;
typedef __attribute__((address_space(3))) unsigned int lds_u32;

__device__ __forceinline__ void dma16(const float* g, float* l) {
    // async global->LDS, 16 B/lane; LDS dest = uniform base + lane*16
    __builtin_amdgcn_global_load_lds((gbl_u32*)g, (lds_u32*)l, 16, 0, 0);
}

__device__ __forceinline__ void split3(float x, unsigned& h1, unsigned& h2, unsigned& h3) {
    unsigned ux = __float_as_uint(x);
    h1 = ux & 0xFFFF0000u;                       // top 8 mantissa bits
    float r = x - __uint_as_float(h1);           // exact
    h2 = __float_as_uint(r) & 0xFFFF0000u;       // next 8
    float r2 = r - __uint_as_float(h2);          // exact
    h3 = __float_as_uint(r2) & 0xFFFF0000u;      // remaining bits (exact)
}

__global__ __launch_bounds__(512, 2)
void gumbel_slot_mfma(const float* __restrict__ slots,
                      const float* __restrict__ gumbel_u,
                      const float* __restrict__ fix_u,
                      const float* __restrict__ W1,
                      const float* __restrict__ b1,
                      const float* __restrict__ W2,
                      const float* __restrict__ b2,
                      float* __restrict__ out)
{
    __shared__ __align__(16) unsigned short wt[3 * 64 * 128];  // 48 KB W1 splits
    __shared__ __align__(16) float red[8][16][16][2];          // 16 KB epilogue
    __shared__ __align__(16) float stg[2][8][1024];            // 2 x 4 KB/wave = 64 KB

    const int tid  = threadIdx.x;
    const int wv   = tid >> 6;        // wave 0..7
    const int lane = tid & 63;
    const int quad = lane >> 4;       // 0..3
    const int col  = lane & 15;       // 0..15
    const bool hiLane = (col >= 8);   // these lanes' rows come via direct loads

    const int lrow = lane >> 5;       // DMA: which of the 2 rows per 1KB instr
    const int lgrn = lane & 31;       // DMA: granule slot within row

    const int tile0 = blockIdx.x * 4;               // 4 consecutive tiles/block
    const int row0  = tile0 * 512 + wv * 64;        // wave's first row

    // direct-load double buffer: parity = mt&1 (compile-time after unroll)
    f32x4 dir[2][8];

    // ---- prologue: stage phase (t=0, mt=0) on both paths ----
    {
        // rows 8..15 direct (col>=8 lanes): granules ks*8+quad*2+{0,1}
        if (hiLane) {
            const float* rp = slots + (size_t)(row0 + col) * D + quad * 8;
#pragma unroll
            for (int k = 0; k < 8; ++k)
                dir[0][k] = *(const f32x4*)(rp + (k >> 1) * 32 + (k & 1) * 4);
        }
        // rows 0..7 via DMA: 4 contiguous 1KB instrs, granule XOR (lgrn^row)
#pragma unroll
        for (int j = 0; j < 4; ++j) {
            const int rsub = 2 * j + lrow;
            dma16(slots + (size_t)(row0 + rsub) * D + ((lgrn ^ rsub) << 2),
                  &stg[0][wv][j * 256]);
        }
    }

    // ---- one-time: split W1 into 3 bf16 planes, transposed [j][d] ----
#pragma unroll
    for (int i = 0; i < 16; ++i) {
        const int e = i * 512 + tid;          // 8192 elements, coalesced
        const int d = e >> 6, j = e & 63;
        unsigned h1, h2, h3;
        split3(W1[e], h1, h2, h3);
        const int chunk = (d >> 3) ^ (j & 15);           // 16B-chunk swizzle
        const int idx = j * 128 + chunk * 8 + (d & 7);
        wt[idx]             = (unsigned short)(h1 >> 16);
        wt[idx + 8192]      = (unsigned short)(h2 >> 16);
        wt[idx + 16384]     = (unsigned short)(h3 >> 16);
    }

    // per-lane constants + ALL gumbel pairs (pre-barrier so the barrier's
    // drain absorbs them; a mid-loop gu load would force a vmcnt(0) drain)
    float  b1v[4];
    float2 w2v[4];
#pragma unroll
    for (int nt = 0; nt < 4; ++nt) {
        b1v[nt] = b1[nt * 16 + col];
        w2v[nt] = *(const float2*)(W2 + (size_t)(nt * 16 + col) * 2);
    }
    const float2 b2v = *(const float2*)b2;
    float2 gu0, gu1, gu2, gu3;
    {
        const size_t rb = (size_t)(row0 + lane);
        gu0 = *(const float2*)(gumbel_u + (rb         ) * 2);
        gu1 = *(const float2*)(gumbel_u + (rb +  512  ) * 2);
        gu2 = *(const float2*)(gumbel_u + (rb + 1024  ) * 2);
        gu3 = *(const float2*)(gumbel_u + (rb + 1536  ) * 2);
    }

    __syncthreads();   // wt ready; drains prologue loads (data persists)

#pragma unroll 1
    for (int t = 0; t < 4; ++t) {
        const int rowW = (tile0 + t) * 512 + wv * 64;    // this wave's 64 rows
        const int r    = rowW + lane;

        f32x4 acc[4][4];
#pragma unroll
        for (int mt = 0; mt < 4; ++mt)
#pragma unroll
            for (int nt = 0; nt < 4; ++nt)
                acc[mt][nt] = f32x4{b1v[nt], b1v[nt], b1v[nt], b1v[nt]};

#pragma unroll
        for (int mt = 0; mt < 4; ++mt) {
            const int cur = mt & 1, nxt = (mt + 1) & 1;   // compile-time

            // ---- 1) issue NEXT phase on both paths (stays in flight) ----
            const bool last = (t == 3) && (mt == 3);
            if (!last) {
                const int rowNbase = (mt < 3) ? (rowW + (mt + 1) * 16)
                                              : (rowW + 512);   // next tile mt0
                if (hiLane) {
                    const float* rp = slots + (size_t)(rowNbase + col) * D + quad * 8;
#pragma unroll
                    for (int k = 0; k < 8; ++k)
                        dir[nxt][k] = *(const f32x4*)(rp + (k >> 1) * 32 + (k & 1) * 4);
                }
#pragma unroll
                for (int j = 0; j < 4; ++j) {
                    const int rsub = 2 * j + lrow;
                    dma16(slots + (size_t)(rowNbase + rsub) * D + ((lgrn ^ rsub) << 2),
                          &stg[nxt][wv][j * 256]);
                }
                // oldest 12 (this phase's 8 direct + 4 dma) must land; the 12
                // just issued stay outstanding. Stores/epilogue ops are older
                // than the new 12 -> also drained: conservative-safe.
                asm volatile("s_waitcnt vmcnt(12)" ::: "memory");
            } else {
                asm volatile("s_waitcnt vmcnt(0)" ::: "memory");
            }
            __builtin_amdgcn_sched_barrier(0);

            // ---- 2) gather this phase's fragments ----
            f32x4 va[4], vb[4];
            if (!hiLane) {
                const float* bufc = &stg[cur][wv][0] + col * 128;
#pragma unroll
                for (int ks = 0; ks < 4; ++ks) {
                    const int i0 = ks * 8 + quad * 2;
                    va[ks] = *(const f32x4*)(bufc + (((i0    ) ^ col) << 2));
                    vb[ks] = *(const f32x4*)(bufc + (((i0 + 1) ^ col) << 2));
                }
            } else {
#pragma unroll
                for (int ks = 0; ks < 4; ++ks) {
                    va[ks] = dir[cur][2 * ks];
                    vb[ks] = dir[cur][2 * ks + 1];
                }
            }
            asm volatile("s_waitcnt lgkmcnt(0)" ::: "memory");
            __builtin_amdgcn_sched_barrier(0);

            // ---- 3) convert + MFMA (order bit-identical per chain) ----
#pragma unroll
            for (int ks = 0; ks < 4; ++ks) {
                const float xs[8] = {va[ks][0], va[ks][1], va[ks][2], va[ks][3],
                                     vb[ks][0], vb[ks][1], vb[ks][2], vb[ks][3]};
                union { int i[4]; bf16x8 vv; } u1, u2, u3;
#pragma unroll
                for (int p = 0; p < 4; ++p) {
                    unsigned xh1, xh2, xh3, yh1, yh2, yh3;
                    split3(xs[2 * p],     xh1, xh2, xh3);
                    split3(xs[2 * p + 1], yh1, yh2, yh3);
                    u1.i[p] = (int)((xh1 >> 16) | yh1);  // [k even | k odd]
                    u2.i[p] = (int)((xh2 >> 16) | yh2);
                    u3.i[p] = (int)((xh3 >> 16) | yh3);
                }
                const bf16x8 a1 = u1.vv, a2 = u2.vv, a3 = u3.vv;

                __builtin_amdgcn_s_setprio(1);
#pragma unroll
                for (int nt = 0; nt < 4; ++nt) {
                    const int j = nt * 16 + col;
                    const int chunk = (ks * 4 + quad) ^ col;
                    const unsigned short* wp = &wt[j * 128 + chunk * 8];
                    const bf16x8 bq1 = *(const bf16x8*)(wp);
                    const bf16x8 bq2 = *(const bf16x8*)(wp + 8192);
                    const bf16x8 bq3 = *(const bf16x8*)(wp + 16384);
                    f32x4 c = acc[mt][nt];
                    c = __builtin_amdgcn_mfma_f32_16x16x32_bf16(a1, bq1, c, 0, 0, 0);
                    c = __builtin_amdgcn_mfma_f32_16x16x32_bf16(a2, bq1, c, 0, 0, 0);
                    c = __builtin_amdgcn_mfma_f32_16x16x32_bf16(a1, bq2, c, 0, 0, 0);
                    c = __builtin_amdgcn_mfma_f32_16x16x32_bf16(a2, bq2, c, 0, 0, 0);
                    c = __builtin_amdgcn_mfma_f32_16x16x32_bf16(a1, bq3, c, 0, 0, 0);
                    c = __builtin_amdgcn_mfma_f32_16x16x32_bf16(a3, bq1, c, 0, 0, 0);
                    acc[mt][nt] = c;
                }
                __builtin_amdgcn_s_setprio(0);
            }
        }

        // ---- epilogue: layer2 partials + per-row transpose via LDS ----
        // Fully unrolled (static acc indices); red[wv] is wave-private.
        float fl0 = 0.f, fl1 = 0.f;
#pragma unroll
        for (int mt = 0; mt < 4; ++mt) {
#pragma unroll
            for (int reg = 0; reg < 4; ++reg) {
                float p0 = 0.f, p1 = 0.f;
#pragma unroll
                for (int nt = 0; nt < 4; ++nt) {
                    const float h = fmaxf(acc[mt][nt][reg], 0.f);
                    p0 = fmaf(h, w2v[nt].x, p0);
                    p1 = fmaf(h, w2v[nt].y, p1);
                }
                const int rl = quad * 4 + reg;
                *(float2*)&red[wv][rl][col ^ rl][0] = make_float2(p0, p1);
            }
            __builtin_amdgcn_wave_barrier();
            if (quad == mt) {
                const int rl = col;
                float s0 = 0.f, s1 = 0.f;
#pragma unroll
                for (int c = 0; c < 16; ++c) {
                    const float2 vv = *(const float2*)&red[wv][rl][c ^ rl][0];
                    s0 += vv.x; s1 += vv.y;
                }
                fl0 = s0; fl1 = s1;
            }
            __builtin_amdgcn_wave_barrier();
        }
        const float l0 = fl0 + b2v.x;
        const float l1 = fl1 + b2v.y;

        // ---- gumbel decision + keep prob ----
        const float2 guv = (t == 0) ? gu0 : ((t == 1) ? gu1 : ((t == 2) ? gu2 : gu3));
        const float lo = 1e-10f, hi = (float)(1.0 - 1e-7);
        const float u0 = fminf(fmaxf(guv.x, lo), hi);
        const float u1 = fminf(fmaxf(guv.y, lo), hi);
        const float g0 = -logf(-logf(u0));
        const float g1 = -logf(-logf(u1));
        float dec = ((l1 + g1) > (l0 + g0)) ? 1.0f : 0.0f;

        const float m  = fmaxf(l0, l1);
        const float e0 = expf(l0 - m), e1 = expf(l1 - m);
        const float keep = e1 / (e0 + e1);

        // ensure-minimum: this wave's 64 lanes == one b's 64 slots
        const unsigned long long act = __ballot(dec != 0.0f);
        if (act == 0ull) {
            float v = fix_u[r];
            int  idx = lane;
#pragma unroll
            for (int off = 32; off > 0; off >>= 1) {
                const float ov  = __shfl_xor(v, off, 64);
                const int  oidx = __shfl_xor(idx, off, 64);
                if (ov > v || (ov == v && oidx < idx)) { v = ov; idx = oidx; }
            }
            if (lane == idx) dec = 1.0f;
        }

        out[r] = dec;
        out[NROWS + r] = keep;
    }
}

extern "C" void kernel_launch(void* const* d_in, const int* in_sizes, int n_in,
                              void* d_out, int out_size, void* d_ws, size_t ws_size,
                              hipStream_t stream)
{
    const float* slots  = (const float*)d_in[0];
    const float* gumbel = (const float*)d_in[1];
    const float* fixu   = (const float*)d_in[2];
    const float* W1     = (const float*)d_in[3];
    const float* b1     = (const float*)d_in[4];
    const float* W2     = (const float*)d_in[5];
    const float* b2     = (const float*)d_in[6];
    float* out = (float*)d_out;

    gumbel_slot_mfma<<<256, 512, 0, stream>>>(
        slots, gumbel, fixu, W1, b1, W2, b2, out);
}